// Round 5
// baseline (878.416 us; speedup 1.0000x reference)
//
#include <hip/hip_runtime.h>
#include <hip/hip_bf16.h>

#define N_NODES 50000
#define N_EDGES 800000
#define N_GRAPHS 128
#define HID 128
#define NK 3
#define NL 4
#define NC 10
#define BN_EPS 1e-5f
#define SCAN_G ((N_NODES + 255) / 256)

typedef __attribute__((ext_vector_type(8))) short short8;
typedef __attribute__((ext_vector_type(4))) float floatx4;
typedef __attribute__((ext_vector_type(2))) _Float16 half2v;
typedef __attribute__((ext_vector_type(4))) _Float16 half4v;

__device__ __forceinline__ float tanh_fast(float x) {
    float ax = fabsf(x);
    float t = __expf(-2.0f * ax);
    float r = (1.0f - t) / (1.0f + t);
    return copysignf(r, x);
}

__device__ __forceinline__ unsigned short f2bf(float f) {
    unsigned u = __float_as_uint(f);
    unsigned r = (u + 0x7FFFu + ((u >> 16) & 1u)) >> 16;
    return (unsigned short)r;
}
__device__ __forceinline__ float bf2f(unsigned short s) {
    return __uint_as_float(((unsigned)s) << 16);
}

// ---------------------------------------------------------------- degrees
__global__ void degrees_kernel(const int* __restrict__ row, const int* __restrict__ col,
                               int* __restrict__ degr, int* __restrict__ degc) {
    int e = blockIdx.x * blockDim.x + threadIdx.x;
    if (e >= N_EDGES) return;
    atomicAdd(&degr[row[e]], 1);
    atomicAdd(&degc[col[e]], 1);
}

// ------------------------------------------------ hierarchical scan (3 kernels)
__global__ __launch_bounds__(256) void scan1_kernel(const int* __restrict__ degc,
                                                    int* __restrict__ csr_off,
                                                    int* __restrict__ blocksum) {
    __shared__ int buf[256];
    int tid = threadIdx.x;
    int i = blockIdx.x * 256 + tid;
    int v = (i < N_NODES) ? degc[i] : 0;
    buf[tid] = v;
    __syncthreads();
    for (int d = 1; d < 256; d <<= 1) {
        int t = (tid >= d) ? buf[tid - d] : 0;
        __syncthreads();
        buf[tid] += t;
        __syncthreads();
    }
    if (i < N_NODES) csr_off[i] = buf[tid] - v;
    if (tid == 255) blocksum[blockIdx.x] = buf[255];
}

__global__ __launch_bounds__(256) void scan2_kernel(int* __restrict__ blocksum) {
    __shared__ int buf[256];
    int tid = threadIdx.x;
    int v = (tid < SCAN_G) ? blocksum[tid] : 0;
    buf[tid] = v;
    __syncthreads();
    for (int d = 1; d < 256; d <<= 1) {
        int t = (tid >= d) ? buf[tid - d] : 0;
        __syncthreads();
        buf[tid] += t;
        __syncthreads();
    }
    if (tid < SCAN_G) blocksum[tid] = buf[tid] - v;   // exclusive, in place
}

__global__ __launch_bounds__(256) void scan3_kernel(const int* __restrict__ blocksum,
                                                    int* __restrict__ csr_off,
                                                    int* __restrict__ cursor) {
    int i = blockIdx.x * 256 + threadIdx.x;
    if (i < N_NODES) {
        int v = csr_off[i] + blocksum[blockIdx.x];
        csr_off[i] = v;
        cursor[i] = v;
    }
    if (i == 0) csr_off[N_NODES] = N_EDGES;
}

// ------------------------- counting-sort scatter: CSR-ordered row + pseudo
__global__ void fill_csr_kernel(const int* __restrict__ row, const int* __restrict__ col,
                                const int* __restrict__ degr, const int* __restrict__ degc,
                                int* __restrict__ cursor, int* __restrict__ row_s,
                                float2* __restrict__ pseudo_s) {
    int e = blockIdx.x * blockDim.x + threadIdx.x;
    if (e >= N_EDGES) return;
    int r = row[e], c = col[e];
    int pos = atomicAdd(&cursor[c], 1);
    row_s[pos] = r;
    pseudo_s[pos] = make_float2(rsqrtf((float)degr[r] + 1.0f), rsqrtf((float)degc[c] + 1.0f));
}

// -------------------- per-edge weights for ALL layers in one pass
__global__ void edge_w_all_kernel(const float2* __restrict__ ps_in,
                                  const float* __restrict__ pp_w, const float* __restrict__ pp_b,
                                  const float* __restrict__ mu, const float* __restrict__ isig,
                                  float4* __restrict__ wE) {
    int e = blockIdx.x * blockDim.x + threadIdx.x;
    if (e >= N_EDGES) return;
    float2 p = ps_in[e];
#pragma unroll
    for (int l = 0; l < NL; ++l) {
        float ps0 = tanh_fast(p.x * pp_w[l * 4 + 0] + p.y * pp_w[l * 4 + 1] + pp_b[l * 2 + 0]);
        float ps1 = tanh_fast(p.x * pp_w[l * 4 + 2] + p.y * pp_w[l * 4 + 3] + pp_b[l * 2 + 1]);
        float w[NK];
#pragma unroll
        for (int k = 0; k < NK; ++k) {
            float d0 = ps0 - mu[l * 6 + k * 2 + 0], d1 = ps1 - mu[l * 6 + k * 2 + 1];
            float s0 = isig[l * 6 + k * 2 + 0],     s1 = isig[l * 6 + k * 2 + 1];
            w[k] = __expf(-0.5f * (d0 * d0 * s0 * s0 + d1 * d1 * s1 * s1));
        }
        wE[(size_t)l * N_EDGES + e] = make_float4(w[0], w[1], w[2], 0.0f);
    }
}

// ------------------------------- element-wise fp32 -> (hi,lo) bf16 split
__global__ void split_kernel(const float* __restrict__ src, unsigned short* __restrict__ hi,
                             unsigned short* __restrict__ lo, int n) {
    int i = blockIdx.x * blockDim.x + threadIdx.x;
    if (i >= n) return;
    float f = src[i];
    unsigned short h = f2bf(f);
    hi[i] = h;
    lo[i] = f2bf(f - bf2f(h));
}

// ---------- fc_w transpose + split: w2t[l][j][k*H+i] = fc_w[l][k*H+j][i]
__global__ void transpose_split_fc_kernel(const float* __restrict__ fc_w,
                                          unsigned short* __restrict__ w2t_hi,
                                          unsigned short* __restrict__ w2t_lo) {
    int idx = blockIdx.x * blockDim.x + threadIdx.x;
    if (idx >= NL * NK * HID * HID) return;
    int i = idx & (HID - 1);
    int j = (idx >> 7) & (HID - 1);
    int kl = idx >> 14;          // l*3 + k
    int k = kl % 3;
    int l = kl / 3;
    float f = fc_w[idx];
    unsigned short h = f2bf(f);
    size_t dst = ((size_t)(l * HID + j)) * (NK * HID) + k * HID + i;
    w2t_hi[dst] = h;
    w2t_lo[dst] = f2bf(f - bf2f(h));
}

// -------------------------------------------------- split-bf16 MFMA GEMM
// C[M x 128] = A[M x Kd] @ W[128 x Kd]^T (+bias). Optional fused BN stats,
// optional fp16 shadow copy of C. 64-row block tile (782 blocks at M=50000).
__global__ __launch_bounds__(256) void gemm_mfma_kernel(
        const unsigned short* __restrict__ A_hi, const unsigned short* __restrict__ A_lo,
        const unsigned short* __restrict__ W_hi, const unsigned short* __restrict__ W_lo,
        const float* __restrict__ bias, float* __restrict__ C, _Float16* __restrict__ C16,
        float* __restrict__ bnsum, int M, int Kd) {
    __shared__ unsigned short sAh[64 * 40], sAl[64 * 40];
    __shared__ unsigned short sBh[128 * 40], sBl[128 * 40];
    __shared__ float bsum[HID], bsq[HID];
    int tid = threadIdx.x;
    if (bnsum && tid < HID) { bsum[tid] = 0.f; bsq[tid] = 0.f; }
    int bm = blockIdx.x * 64;
    int wave = tid >> 6, lane = tid & 63;
    int ln = lane & 15, quad = lane >> 4;
    int wy = wave >> 1, wx = wave & 1;
    int srow = tid >> 2, scol = (tid & 3) << 3;
    floatx4 acc[2][4] = {};
    const short8 zv = {0, 0, 0, 0, 0, 0, 0, 0};

    short8 pAh, pAl, pBh[2], pBl[2];
    bool av = (bm + srow) < M;
    const size_t aoff  = (size_t)(bm + srow) * Kd + scol;
    const size_t woff0 = (size_t)srow * Kd + scol;
    const size_t woff1 = (size_t)(srow + 64) * Kd + scol;

#define LOAD_TILE(K0)                                                          \
    do {                                                                       \
        pBh[0] = *(const short8*)(W_hi + woff0 + (K0));                        \
        pBl[0] = *(const short8*)(W_lo + woff0 + (K0));                        \
        pBh[1] = *(const short8*)(W_hi + woff1 + (K0));                        \
        pBl[1] = *(const short8*)(W_lo + woff1 + (K0));                        \
        pAh = av ? *(const short8*)(A_hi + aoff + (K0)) : zv;                  \
        pAl = av ? *(const short8*)(A_lo + aoff + (K0)) : zv;                  \
    } while (0)

    LOAD_TILE(0);
    for (int k0 = 0; k0 < Kd; k0 += 32) {
        __syncthreads();
        *(short8*)&sAh[srow * 40 + scol] = pAh;
        *(short8*)&sAl[srow * 40 + scol] = pAl;
        *(short8*)&sBh[srow * 40 + scol] = pBh[0];
        *(short8*)&sBl[srow * 40 + scol] = pBl[0];
        *(short8*)&sBh[(srow + 64) * 40 + scol] = pBh[1];
        *(short8*)&sBl[(srow + 64) * 40 + scol] = pBl[1];
        __syncthreads();
        if (k0 + 32 < Kd) LOAD_TILE(k0 + 32);   // overlaps with MFMA below
        short8 ah[2], al[2], bh[4], bl[4];
        int kq = quad * 8;
#pragma unroll
        for (int i = 0; i < 2; ++i) {
            int ra = wy * 32 + i * 16 + ln;
            ah[i] = *(const short8*)&sAh[ra * 40 + kq];
            al[i] = *(const short8*)&sAl[ra * 40 + kq];
        }
#pragma unroll
        for (int j = 0; j < 4; ++j) {
            int rb = wx * 64 + j * 16 + ln;
            bh[j] = *(const short8*)&sBh[rb * 40 + kq];
            bl[j] = *(const short8*)&sBl[rb * 40 + kq];
        }
#pragma unroll
        for (int i = 0; i < 2; ++i)
#pragma unroll
            for (int j = 0; j < 4; ++j) {
                acc[i][j] = __builtin_amdgcn_mfma_f32_16x16x32_bf16(ah[i], bh[j], acc[i][j], 0, 0, 0);
                acc[i][j] = __builtin_amdgcn_mfma_f32_16x16x32_bf16(ah[i], bl[j], acc[i][j], 0, 0, 0);
                acc[i][j] = __builtin_amdgcn_mfma_f32_16x16x32_bf16(al[i], bh[j], acc[i][j], 0, 0, 0);
            }
    }
#undef LOAD_TILE

    // epilogue: C/D layout col = lane&15, row = quad*4 + reg
#pragma unroll
    for (int j = 0; j < 4; ++j) {
        int gc = wx * 64 + j * 16 + ln;
        float bv = bias ? bias[gc] : 0.f;
#pragma unroll
        for (int i = 0; i < 2; ++i) {
#pragma unroll
            for (int r = 0; r < 4; ++r) {
                int gr = bm + wy * 32 + i * 16 + quad * 4 + r;
                if (gr < M) {
                    float v = acc[i][j][r] + bv;
                    C[(size_t)gr * HID + gc] = v;
                    if (C16) C16[(size_t)gr * HID + gc] = (_Float16)v;
                }
            }
        }
    }
    if (bnsum) {
#pragma unroll
        for (int j = 0; j < 4; ++j) {
            float s = 0.f, q = 0.f;
#pragma unroll
            for (int i = 0; i < 2; ++i)
#pragma unroll
                for (int r = 0; r < 4; ++r) {
                    if (bm + wy * 32 + i * 16 + quad * 4 + r < M) {
                        float v = acc[i][j][r]; s += v; q += v * v;
                    }
                }
            s += __shfl_xor(s, 16); s += __shfl_xor(s, 32);
            q += __shfl_xor(q, 16); q += __shfl_xor(q, 32);
            if (quad == 0) {
                atomicAdd(&bsum[wx * 64 + j * 16 + ln], s);
                atomicAdd(&bsq[wx * 64 + j * 16 + ln], q);
            }
        }
        __syncthreads();
        if (tid < HID) {
            atomicAdd(&bnsum[tid],       bsum[tid]);
            atomicAdd(&bnsum[HID + tid], bsq[tid]);
        }
    }
}

// ----------- CSR aggregation gathering fp16 h; emits u as (hi,lo) bf16 [N][384]
// edge loop unrolled x8 (8 independent 4B/lane gathers in flight)
__global__ __launch_bounds__(256) void aggregate_kernel(const int* __restrict__ csr_off,
                                                        const int* __restrict__ row_s,
                                                        const float4* __restrict__ wE,
                                                        const half2v* __restrict__ h16,
                                                        unsigned short* __restrict__ u_hi,
                                                        unsigned short* __restrict__ u_lo) {
    int wave = threadIdx.x >> 6;
    int lane = threadIdx.x & 63;
    int n = blockIdx.x * 4 + wave;
    if (n >= N_NODES) return;
    int beg = csr_off[n], end = csr_off[n + 1];
    float2 a0 = {0.f, 0.f}, a1 = {0.f, 0.f}, a2 = {0.f, 0.f};
    for (int e = beg; e < end; e += 8) {
        int rr[8]; float4 ww[8];
#pragma unroll
        for (int t = 0; t < 8; ++t) {
            int idx = e + t;
            bool v = idx < end;
            int ci = v ? idx : (end - 1);
            rr[t] = row_s[ci];
            float4 w = wE[ci];
            ww[t] = v ? w : make_float4(0.f, 0.f, 0.f, 0.f);
        }
        half2v hv[8];
#pragma unroll
        for (int t = 0; t < 8; ++t) hv[t] = h16[(size_t)rr[t] * 64 + lane];
#pragma unroll
        for (int t = 0; t < 8; ++t) {
            float hx = (float)hv[t].x, hy = (float)hv[t].y;
            a0.x += ww[t].x * hx; a0.y += ww[t].x * hy;
            a1.x += ww[t].y * hx; a1.y += ww[t].y * hy;
            a2.x += ww[t].z * hx; a2.y += ww[t].z * hy;
        }
    }
    size_t base = (size_t)n * 384 + lane * 2;
    float2 vals[3] = {a0, a1, a2};
#pragma unroll
    for (int k = 0; k < 3; ++k) {
        unsigned short hx = f2bf(vals[k].x), hy = f2bf(vals[k].y);
        ushort2 hv, lv;
        hv.x = hx; hv.y = hy;
        lv.x = f2bf(vals[k].x - bf2f(hx));
        lv.y = f2bf(vals[k].y - bf2f(hy));
        *(ushort2*)(u_hi + base + k * 128) = hv;
        *(ushort2*)(u_lo + base + k * 128) = lv;
    }
}

// --------------------- BN apply + ReLU + residual; also writes fp16 shadow
__global__ void bn_apply_kernel(float4* __restrict__ h4, half4v* __restrict__ h16,
                                const float4* __restrict__ agg4,
                                const float* __restrict__ bnsum,
                                const float* __restrict__ gamma, const float* __restrict__ beta) {
    int idx = blockIdx.x * blockDim.x + threadIdx.x;
    if (idx >= N_NODES * HID / 4) return;
    int c = (idx & 31) * 4;
    const float invN = 1.0f / (float)N_NODES;
    float4 a = agg4[idx];
    float4 hv = h4[idx];
    float av[4] = {a.x, a.y, a.z, a.w};
    float hh[4] = {hv.x, hv.y, hv.z, hv.w};
    float o[4];
    half4v o16;
#pragma unroll
    for (int j = 0; j < 4; ++j) {
        float mean = bnsum[c + j] * invN;
        float var = bnsum[HID + c + j] * invN - mean * mean;
        float hn = (av[j] - mean) * rsqrtf(var + BN_EPS) * gamma[c + j] + beta[c + j];
        o[j] = hh[j] + fmaxf(hn, 0.f);
        o16[j] = (_Float16)o[j];
    }
    h4[idx] = make_float4(o[0], o[1], o[2], o[3]);
    h16[idx] = o16;
}

// -------------------------------------------- fused readout + 3-layer MLP
__global__ __launch_bounds__(128) void readout_mlp_kernel(const float* __restrict__ h,
                                                          const int* __restrict__ batch,
                                                          const float* __restrict__ w0, const float* __restrict__ b0,
                                                          const float* __restrict__ w1, const float* __restrict__ b1,
                                                          const float* __restrict__ w2, const float* __restrict__ b2,
                                                          float* __restrict__ out) {
    __shared__ float hg[128];
    __shared__ float z0[64];
    __shared__ float z1[32];
    __shared__ int range[2];
    int g = blockIdx.x;
    int tid = threadIdx.x;
    if (tid == 0) {
        int lo = 0, hi = N_NODES;
        while (lo < hi) { int mid = (lo + hi) >> 1; if (batch[mid] < g) lo = mid + 1; else hi = mid; }
        range[0] = lo;
        hi = N_NODES;
        while (lo < hi) { int mid = (lo + hi) >> 1; if (batch[mid] < g + 1) lo = mid + 1; else hi = mid; }
        range[1] = lo;
    }
    __syncthreads();
    int lo = range[0], hi = range[1];
    float s0 = 0.f, s1 = 0.f, s2 = 0.f, s3 = 0.f;
    int n = lo;
    for (; n + 4 <= hi; n += 4) {
        s0 += h[(size_t)n * HID + tid];
        s1 += h[(size_t)(n + 1) * HID + tid];
        s2 += h[(size_t)(n + 2) * HID + tid];
        s3 += h[(size_t)(n + 3) * HID + tid];
    }
    for (; n < hi; ++n) s0 += h[(size_t)n * HID + tid];
    float s = (s0 + s1) + (s2 + s3);
    int cnt = hi - lo; if (cnt < 1) cnt = 1;
    hg[tid] = s / (float)cnt;
    __syncthreads();
    if (tid < 64) {
        float a = b0[tid];
        for (int i = 0; i < 128; ++i) a += hg[i] * w0[tid * 128 + i];
        z0[tid] = fmaxf(a, 0.f);
    }
    __syncthreads();
    if (tid < 32) {
        float a = b1[tid];
        for (int i = 0; i < 64; ++i) a += z0[i] * w1[tid * 64 + i];
        z1[tid] = fmaxf(a, 0.f);
    }
    __syncthreads();
    if (tid < 10) {
        float a = b2[tid];
        for (int i = 0; i < 32; ++i) a += z1[i] * w2[tid * 32 + i];
        out[g * NC + tid] = a;
    }
}

// ----------------------------------------------------------------- launch
extern "C" void kernel_launch(void* const* d_in, const int* in_sizes, int n_in,
                              void* d_out, int out_size, void* d_ws, size_t ws_size,
                              hipStream_t stream) {
    const float* feature = (const float*)d_in[0];
    const int*   edge    = (const int*)d_in[1];
    const int*   row     = edge;
    const int*   col     = edge + N_EDGES;
    const int*   batch   = (const int*)d_in[2];
    const float* emb_w   = (const float*)d_in[3];
    const float* emb_b   = (const float*)d_in[4];
    const float* fc_w    = (const float*)d_in[5];
    const float* mu      = (const float*)d_in[6];
    const float* isig    = (const float*)d_in[7];
    const float* gamma   = (const float*)d_in[8];
    const float* beta    = (const float*)d_in[9];
    const float* pp_w    = (const float*)d_in[10];
    const float* pp_b    = (const float*)d_in[11];
    const float* mw0     = (const float*)d_in[12];
    const float* mb0     = (const float*)d_in[13];
    const float* mw1     = (const float*)d_in[14];
    const float* mb1     = (const float*)d_in[15];
    const float* mw2     = (const float*)d_in[16];
    const float* mb2     = (const float*)d_in[17];
    float* out = (float*)d_out;

    // workspace carve-up (256B aligned)
    char* ws = (char*)d_ws;
    size_t off = 0;
    auto carve = [&](size_t bytes) { size_t o = off; off = (off + bytes + 255) & ~(size_t)255; return o; };
    float* h        = (float*)(ws + carve((size_t)N_NODES * HID * 4));
    _Float16* h16   = (_Float16*)(ws + carve((size_t)N_NODES * HID * 2));
    unsigned short* u_hi = (unsigned short*)(ws + carve((size_t)N_NODES * NK * HID * 2));
    unsigned short* u_lo = (unsigned short*)(ws + carve((size_t)N_NODES * NK * HID * 2));
    float* agg      = (float*)(ws + carve((size_t)N_NODES * HID * 4));
    float2* pseudo_s= (float2*)(ws + carve((size_t)N_EDGES * 2 * 4));
    float4* wE      = (float4*)(ws + carve((size_t)NL * N_EDGES * 4 * 4));
    unsigned short* w2t_hi = (unsigned short*)(ws + carve((size_t)NL * HID * NK * HID * 2));
    unsigned short* w2t_lo = (unsigned short*)(ws + carve((size_t)NL * HID * NK * HID * 2));
    unsigned short* f_hi   = (unsigned short*)(ws + carve((size_t)N_NODES * HID * 2));
    unsigned short* f_lo   = (unsigned short*)(ws + carve((size_t)N_NODES * HID * 2));
    unsigned short* e_hi   = (unsigned short*)(ws + carve((size_t)HID * HID * 2));
    unsigned short* e_lo   = (unsigned short*)(ws + carve((size_t)HID * HID * 2));
    int* degr       = (int*)(ws + carve((size_t)N_NODES * 4));
    int* degc       = (int*)(ws + carve((size_t)N_NODES * 4));
    int* csr_off    = (int*)(ws + carve((size_t)(N_NODES + 1) * 4));
    int* cursor     = (int*)(ws + carve((size_t)N_NODES * 4));
    int* row_s      = (int*)(ws + carve((size_t)N_EDGES * 4));
    int* blocksum   = (int*)(ws + carve((size_t)SCAN_G * 4));
    float* bnsum    = (float*)(ws + carve((size_t)NL * 2 * HID * 4));
    (void)ws_size; (void)in_sizes; (void)n_in; (void)out_size;

    hipMemsetAsync(degr, 0, (size_t)N_NODES * 4, stream);
    hipMemsetAsync(degc, 0, (size_t)N_NODES * 4, stream);
    hipMemsetAsync(bnsum, 0, (size_t)NL * 2 * HID * 4, stream);

    degrees_kernel<<<(N_EDGES + 255) / 256, 256, 0, stream>>>(row, col, degr, degc);
    scan1_kernel<<<SCAN_G, 256, 0, stream>>>(degc, csr_off, blocksum);
    scan2_kernel<<<1, 256, 0, stream>>>(blocksum);
    scan3_kernel<<<SCAN_G, 256, 0, stream>>>(blocksum, csr_off, cursor);
    fill_csr_kernel<<<(N_EDGES + 255) / 256, 256, 0, stream>>>(row, col, degr, degc, cursor, row_s, pseudo_s);
    edge_w_all_kernel<<<(N_EDGES + 255) / 256, 256, 0, stream>>>(pseudo_s, pp_w, pp_b, mu, isig, wE);

    split_kernel<<<(N_NODES * HID + 255) / 256, 256, 0, stream>>>(feature, f_hi, f_lo, N_NODES * HID);
    split_kernel<<<(HID * HID + 255) / 256, 256, 0, stream>>>(emb_w, e_hi, e_lo, HID * HID);
    transpose_split_fc_kernel<<<(NL * NK * HID * HID + 255) / 256, 256, 0, stream>>>(fc_w, w2t_hi, w2t_lo);

    // h = feature @ emb_w^T + emb_b (writes fp32 h and fp16 shadow)
    gemm_mfma_kernel<<<(N_NODES + 63) / 64, 256, 0, stream>>>(
        f_hi, f_lo, e_hi, e_lo, emb_b, h, h16, nullptr, N_NODES, HID);

    for (int l = 0; l < NL; ++l) {
        aggregate_kernel<<<(N_NODES + 3) / 4, 256, 0, stream>>>(
            csr_off, row_s, wE + (size_t)l * N_EDGES, (const half2v*)h16, u_hi, u_lo);
        gemm_mfma_kernel<<<(N_NODES + 63) / 64, 256, 0, stream>>>(
            u_hi, u_lo, w2t_hi + (size_t)l * HID * NK * HID, w2t_lo + (size_t)l * HID * NK * HID,
            nullptr, agg, nullptr, bnsum + l * 2 * HID, N_NODES, NK * HID);
        bn_apply_kernel<<<(N_NODES * HID / 4 + 255) / 256, 256, 0, stream>>>(
            (float4*)h, (half4v*)h16, (const float4*)agg, bnsum + l * 2 * HID,
            gamma + l * HID, beta + l * HID);
    }

    readout_mlp_kernel<<<N_GRAPHS, 128, 0, stream>>>(h, batch, mw0, mb0, mw1, mb1, mw2, mb2, out);
}

// Round 6
// 677.997 us; speedup vs baseline: 1.2956x; 1.2956x over previous
//
#include <hip/hip_runtime.h>
#include <hip/hip_bf16.h>

#define N_NODES 50000
#define N_EDGES 800000
#define N_GRAPHS 128
#define HID 128
#define NK 3
#define NL 4
#define NC 10
#define BN_EPS 1e-5f
#define SCAN_G ((N_NODES + 255) / 256)

typedef __attribute__((ext_vector_type(8))) short short8;
typedef __attribute__((ext_vector_type(4))) float floatx4;
typedef __attribute__((ext_vector_type(2))) _Float16 half2v;
typedef __attribute__((ext_vector_type(4))) _Float16 half4v;

__device__ __forceinline__ float tanh_fast(float x) {
    float ax = fabsf(x);
    float t = __expf(-2.0f * ax);
    float r = (1.0f - t) / (1.0f + t);
    return copysignf(r, x);
}

__device__ __forceinline__ unsigned short f2bf(float f) {
    unsigned u = __float_as_uint(f);
    unsigned r = (u + 0x7FFFu + ((u >> 16) & 1u)) >> 16;
    return (unsigned short)r;
}
__device__ __forceinline__ float bf2f(unsigned short s) {
    return __uint_as_float(((unsigned)s) << 16);
}

// ---------------------------------------------------------------- degrees
__global__ void degrees_kernel(const int* __restrict__ row, const int* __restrict__ col,
                               int* __restrict__ degr, int* __restrict__ degc) {
    int e = blockIdx.x * blockDim.x + threadIdx.x;
    if (e >= N_EDGES) return;
    atomicAdd(&degr[row[e]], 1);
    atomicAdd(&degc[col[e]], 1);
}

// ------------------------------------------------ hierarchical scan (3 kernels)
__global__ __launch_bounds__(256) void scan1_kernel(const int* __restrict__ degc,
                                                    int* __restrict__ csr_off,
                                                    int* __restrict__ blocksum) {
    __shared__ int buf[256];
    int tid = threadIdx.x;
    int i = blockIdx.x * 256 + tid;
    int v = (i < N_NODES) ? degc[i] : 0;
    buf[tid] = v;
    __syncthreads();
    for (int d = 1; d < 256; d <<= 1) {
        int t = (tid >= d) ? buf[tid - d] : 0;
        __syncthreads();
        buf[tid] += t;
        __syncthreads();
    }
    if (i < N_NODES) csr_off[i] = buf[tid] - v;
    if (tid == 255) blocksum[blockIdx.x] = buf[255];
}

__global__ __launch_bounds__(256) void scan2_kernel(int* __restrict__ blocksum) {
    __shared__ int buf[256];
    int tid = threadIdx.x;
    int v = (tid < SCAN_G) ? blocksum[tid] : 0;
    buf[tid] = v;
    __syncthreads();
    for (int d = 1; d < 256; d <<= 1) {
        int t = (tid >= d) ? buf[tid - d] : 0;
        __syncthreads();
        buf[tid] += t;
        __syncthreads();
    }
    if (tid < SCAN_G) blocksum[tid] = buf[tid] - v;   // exclusive, in place
}

__global__ __launch_bounds__(256) void scan3_kernel(const int* __restrict__ blocksum,
                                                    int* __restrict__ csr_off,
                                                    int* __restrict__ cursor) {
    int i = blockIdx.x * 256 + threadIdx.x;
    if (i < N_NODES) {
        int v = csr_off[i] + blocksum[blockIdx.x];
        csr_off[i] = v;
        cursor[i] = v;
    }
    if (i == 0) csr_off[N_NODES] = N_EDGES;
}

// --------------- counting-sort scatter: CSR-ordered row byte-offset + pseudo
__global__ void fill_csr_kernel(const int* __restrict__ row, const int* __restrict__ col,
                                const int* __restrict__ degr, const int* __restrict__ degc,
                                int* __restrict__ cursor, int* __restrict__ row_off,
                                float2* __restrict__ pseudo_s) {
    int e = blockIdx.x * blockDim.x + threadIdx.x;
    if (e >= N_EDGES) return;
    int r = row[e], c = col[e];
    int pos = atomicAdd(&cursor[c], 1);
    row_off[pos] = r << 8;   // byte offset into fp16 h (256 B per row)
    pseudo_s[pos] = make_float2(rsqrtf((float)degr[r] + 1.0f), rsqrtf((float)degc[c] + 1.0f));
}

// -------------------- per-edge weights for ALL layers in one pass
__global__ void edge_w_all_kernel(const float2* __restrict__ ps_in,
                                  const float* __restrict__ pp_w, const float* __restrict__ pp_b,
                                  const float* __restrict__ mu, const float* __restrict__ isig,
                                  float4* __restrict__ wE) {
    int e = blockIdx.x * blockDim.x + threadIdx.x;
    if (e >= N_EDGES) return;
    float2 p = ps_in[e];
#pragma unroll
    for (int l = 0; l < NL; ++l) {
        float ps0 = tanh_fast(p.x * pp_w[l * 4 + 0] + p.y * pp_w[l * 4 + 1] + pp_b[l * 2 + 0]);
        float ps1 = tanh_fast(p.x * pp_w[l * 4 + 2] + p.y * pp_w[l * 4 + 3] + pp_b[l * 2 + 1]);
        float w[NK];
#pragma unroll
        for (int k = 0; k < NK; ++k) {
            float d0 = ps0 - mu[l * 6 + k * 2 + 0], d1 = ps1 - mu[l * 6 + k * 2 + 1];
            float s0 = isig[l * 6 + k * 2 + 0],     s1 = isig[l * 6 + k * 2 + 1];
            w[k] = __expf(-0.5f * (d0 * d0 * s0 * s0 + d1 * d1 * s1 * s1));
        }
        wE[(size_t)l * N_EDGES + e] = make_float4(w[0], w[1], w[2], 0.0f);
    }
}

// ------------------------------- element-wise fp32 -> (hi,lo) bf16 split
__global__ void split_kernel(const float* __restrict__ src, unsigned short* __restrict__ hi,
                             unsigned short* __restrict__ lo, int n) {
    int i = blockIdx.x * blockDim.x + threadIdx.x;
    if (i >= n) return;
    float f = src[i];
    unsigned short h = f2bf(f);
    hi[i] = h;
    lo[i] = f2bf(f - bf2f(h));
}

// ---------- fc_w transpose + split: w2t[l][j][k*H+i] = fc_w[l][k*H+j][i]
__global__ void transpose_split_fc_kernel(const float* __restrict__ fc_w,
                                          unsigned short* __restrict__ w2t_hi,
                                          unsigned short* __restrict__ w2t_lo) {
    int idx = blockIdx.x * blockDim.x + threadIdx.x;
    if (idx >= NL * NK * HID * HID) return;
    int i = idx & (HID - 1);
    int j = (idx >> 7) & (HID - 1);
    int kl = idx >> 14;          // l*3 + k
    int k = kl % 3;
    int l = kl / 3;
    float f = fc_w[idx];
    unsigned short h = f2bf(f);
    size_t dst = ((size_t)(l * HID + j)) * (NK * HID) + k * HID + i;
    w2t_hi[dst] = h;
    w2t_lo[dst] = f2bf(f - bf2f(h));
}

// -------------------------------------------------- split-bf16 MFMA GEMM
// C[M x 128] = A[M x Kd] @ W[128 x Kd]^T (+bias). 128x128 block tile.
// Optional fused BN stats; optional fp16 shadow of C.
__global__ __launch_bounds__(256) void gemm_mfma_kernel(
        const unsigned short* __restrict__ A_hi, const unsigned short* __restrict__ A_lo,
        const unsigned short* __restrict__ W_hi, const unsigned short* __restrict__ W_lo,
        const float* __restrict__ bias, float* __restrict__ C, _Float16* __restrict__ C16,
        float* __restrict__ bnsum, int M, int Kd) {
    __shared__ unsigned short lds[4 * 128 * 40];   // Ah | Al | Bh | Bl, stride 40
    __shared__ float bsum[HID], bsq[HID];
    unsigned short* sAh = lds;
    unsigned short* sAl = lds + 5120;
    unsigned short* sBh = lds + 10240;
    unsigned short* sBl = lds + 15360;
    int tid = threadIdx.x;
    if (bnsum && tid < HID) { bsum[tid] = 0.f; bsq[tid] = 0.f; }
    int bm = blockIdx.x * 128;
    int wave = tid >> 6, lane = tid & 63;
    int ln = lane & 15, quad = lane >> 4;
    int wy = wave >> 1, wx = wave & 1;
    int srow = tid >> 2, scol = (tid & 3) << 3;
    floatx4 acc[4][4] = {};
    const short8 zv = {0, 0, 0, 0, 0, 0, 0, 0};

    short8 pAh[2], pAl[2], pBh[2], pBl[2];
    bool av0 = (bm + srow) < M, av1 = (bm + srow + 64) < M;
    const size_t aoff0 = (size_t)(bm + srow) * Kd + scol;
    const size_t aoff1 = (size_t)(bm + srow + 64) * Kd + scol;
    const size_t woff0 = (size_t)srow * Kd + scol;
    const size_t woff1 = (size_t)(srow + 64) * Kd + scol;

#define LOAD_TILE(K0)                                                          \
    do {                                                                       \
        pBh[0] = *(const short8*)(W_hi + woff0 + (K0));                        \
        pBl[0] = *(const short8*)(W_lo + woff0 + (K0));                        \
        pBh[1] = *(const short8*)(W_hi + woff1 + (K0));                        \
        pBl[1] = *(const short8*)(W_lo + woff1 + (K0));                        \
        pAh[0] = av0 ? *(const short8*)(A_hi + aoff0 + (K0)) : zv;             \
        pAl[0] = av0 ? *(const short8*)(A_lo + aoff0 + (K0)) : zv;             \
        pAh[1] = av1 ? *(const short8*)(A_hi + aoff1 + (K0)) : zv;             \
        pAl[1] = av1 ? *(const short8*)(A_lo + aoff1 + (K0)) : zv;             \
    } while (0)

    LOAD_TILE(0);
    for (int k0 = 0; k0 < Kd; k0 += 32) {
        __syncthreads();
#pragma unroll
        for (int rep = 0; rep < 2; ++rep) {
            int r = srow + rep * 64;
            *(short8*)&sAh[r * 40 + scol] = pAh[rep];
            *(short8*)&sAl[r * 40 + scol] = pAl[rep];
            *(short8*)&sBh[r * 40 + scol] = pBh[rep];
            *(short8*)&sBl[r * 40 + scol] = pBl[rep];
        }
        __syncthreads();
        if (k0 + 32 < Kd) LOAD_TILE(k0 + 32);   // overlaps with MFMA below
        short8 ah[4], al[4], bh[4], bl[4];
        int kq = quad * 8;
#pragma unroll
        for (int i = 0; i < 4; ++i) {
            int ra = wy * 64 + i * 16 + ln;
            int rb = wx * 64 + i * 16 + ln;
            ah[i] = *(const short8*)&sAh[ra * 40 + kq];
            al[i] = *(const short8*)&sAl[ra * 40 + kq];
            bh[i] = *(const short8*)&sBh[rb * 40 + kq];
            bl[i] = *(const short8*)&sBl[rb * 40 + kq];
        }
#pragma unroll
        for (int i = 0; i < 4; ++i)
#pragma unroll
            for (int j = 0; j < 4; ++j) {
                acc[i][j] = __builtin_amdgcn_mfma_f32_16x16x32_bf16(ah[i], bh[j], acc[i][j], 0, 0, 0);
                acc[i][j] = __builtin_amdgcn_mfma_f32_16x16x32_bf16(ah[i], bl[j], acc[i][j], 0, 0, 0);
                acc[i][j] = __builtin_amdgcn_mfma_f32_16x16x32_bf16(al[i], bh[j], acc[i][j], 0, 0, 0);
            }
    }
#undef LOAD_TILE

    // epilogue: C/D layout col = lane&15, row = quad*4 + reg
#pragma unroll
    for (int j = 0; j < 4; ++j) {
        int gc = wx * 64 + j * 16 + ln;
        float bv = bias ? bias[gc] : 0.f;
#pragma unroll
        for (int i = 0; i < 4; ++i) {
#pragma unroll
            for (int r = 0; r < 4; ++r) {
                int gr = bm + wy * 64 + i * 16 + quad * 4 + r;
                if (gr < M) {
                    float v = acc[i][j][r] + bv;
                    C[(size_t)gr * HID + gc] = v;
                    if (C16) C16[(size_t)gr * HID + gc] = (_Float16)v;
                }
            }
        }
    }
    if (bnsum) {
        // rows beyond M accumulated zeros (A loaded as 0, no bias) -> safe
#pragma unroll
        for (int j = 0; j < 4; ++j) {
            float s = 0.f, q = 0.f;
#pragma unroll
            for (int i = 0; i < 4; ++i)
#pragma unroll
                for (int r = 0; r < 4; ++r) { float v = acc[i][j][r]; s += v; q += v * v; }
            s += __shfl_xor(s, 16); s += __shfl_xor(s, 32);
            q += __shfl_xor(q, 16); q += __shfl_xor(q, 32);
            if (quad == 0) {
                atomicAdd(&bsum[wx * 64 + j * 16 + ln], s);
                atomicAdd(&bsq[wx * 64 + j * 16 + ln], q);
            }
        }
        __syncthreads();
        if (tid < HID) {
            atomicAdd(&bnsum[tid],       bsum[tid]);
            atomicAdd(&bnsum[HID + tid], bsq[tid]);
        }
    }
}

// ----------- CSR aggregation gathering fp16 h; emits u as (hi,lo) bf16 [N][384]
// metadata for up to 64 edges loaded once per wave (coalesced), broadcast via shfl
__global__ __launch_bounds__(256) void aggregate_kernel(const int* __restrict__ csr_off,
                                                        const int* __restrict__ row_off,
                                                        const float4* __restrict__ wE,
                                                        const char* __restrict__ h16,
                                                        unsigned short* __restrict__ u_hi,
                                                        unsigned short* __restrict__ u_lo) {
    int wave = threadIdx.x >> 6;
    int lane = threadIdx.x & 63;
    int n = blockIdx.x * 4 + wave;
    if (n >= N_NODES) return;
    int beg = csr_off[n], end = csr_off[n + 1];
    const char* hb = h16 + lane * 4;
    float2 a0 = {0.f, 0.f}, a1 = {0.f, 0.f}, a2 = {0.f, 0.f};
    for (int chunk = beg; chunk < end; chunk += 64) {
        int ce = chunk + lane;
        int roff = 0;
        float4 wv = make_float4(0.f, 0.f, 0.f, 0.f);
        if (ce < end) { roff = row_off[ce]; wv = wE[ce]; }
        int m = end - chunk; if (m > 64) m = 64;
        int t = 0;
        for (; t + 8 <= m; t += 8) {
            int ro[8]; float wx[8], wy[8], wz[8];
#pragma unroll
            for (int s = 0; s < 8; ++s) {
                ro[s] = __shfl(roff, t + s);
                wx[s] = __shfl(wv.x, t + s);
                wy[s] = __shfl(wv.y, t + s);
                wz[s] = __shfl(wv.z, t + s);
            }
            half2v hv[8];
#pragma unroll
            for (int s = 0; s < 8; ++s) hv[s] = *(const half2v*)(hb + (unsigned)ro[s]);
#pragma unroll
            for (int s = 0; s < 8; ++s) {
                float hx = (float)hv[s].x, hy = (float)hv[s].y;
                a0.x += wx[s] * hx; a0.y += wx[s] * hy;
                a1.x += wy[s] * hx; a1.y += wy[s] * hy;
                a2.x += wz[s] * hx; a2.y += wz[s] * hy;
            }
        }
        for (; t < m; ++t) {
            int ro = __shfl(roff, t);
            float wx = __shfl(wv.x, t), wy = __shfl(wv.y, t), wz = __shfl(wv.z, t);
            half2v hv = *(const half2v*)(hb + (unsigned)ro);
            float hx = (float)hv.x, hy = (float)hv.y;
            a0.x += wx * hx; a0.y += wx * hy;
            a1.x += wy * hx; a1.y += wy * hy;
            a2.x += wz * hx; a2.y += wz * hy;
        }
    }
    size_t base = (size_t)n * 384 + lane * 2;
    float2 vals[3] = {a0, a1, a2};
#pragma unroll
    for (int k = 0; k < 3; ++k) {
        unsigned short hx = f2bf(vals[k].x), hy = f2bf(vals[k].y);
        ushort2 hv, lv;
        hv.x = hx; hv.y = hy;
        lv.x = f2bf(vals[k].x - bf2f(hx));
        lv.y = f2bf(vals[k].y - bf2f(hy));
        *(ushort2*)(u_hi + base + k * 128) = hv;
        *(ushort2*)(u_lo + base + k * 128) = lv;
    }
}

// --------------------- BN apply + ReLU + residual; also writes fp16 shadow
__global__ void bn_apply_kernel(float4* __restrict__ h4, half4v* __restrict__ h16,
                                const float4* __restrict__ agg4,
                                const float* __restrict__ bnsum,
                                const float* __restrict__ gamma, const float* __restrict__ beta) {
    int idx = blockIdx.x * blockDim.x + threadIdx.x;
    if (idx >= N_NODES * HID / 4) return;
    int c = (idx & 31) * 4;
    const float invN = 1.0f / (float)N_NODES;
    float4 a = agg4[idx];
    float4 hv = h4[idx];
    float av[4] = {a.x, a.y, a.z, a.w};
    float hh[4] = {hv.x, hv.y, hv.z, hv.w};
    float o[4];
    half4v o16;
#pragma unroll
    for (int j = 0; j < 4; ++j) {
        float mean = bnsum[c + j] * invN;
        float var = bnsum[HID + c + j] * invN - mean * mean;
        float hn = (av[j] - mean) * rsqrtf(var + BN_EPS) * gamma[c + j] + beta[c + j];
        o[j] = hh[j] + fmaxf(hn, 0.f);
        o16[j] = (_Float16)o[j];
    }
    h4[idx] = make_float4(o[0], o[1], o[2], o[3]);
    h16[idx] = o16;
}

// -------------------------------------------- fused readout + 3-layer MLP
__global__ __launch_bounds__(128) void readout_mlp_kernel(const float* __restrict__ h,
                                                          const int* __restrict__ batch,
                                                          const float* __restrict__ w0, const float* __restrict__ b0,
                                                          const float* __restrict__ w1, const float* __restrict__ b1,
                                                          const float* __restrict__ w2, const float* __restrict__ b2,
                                                          float* __restrict__ out) {
    __shared__ float hg[128];
    __shared__ float z0[64];
    __shared__ float z1[32];
    __shared__ int range[2];
    int g = blockIdx.x;
    int tid = threadIdx.x;
    if (tid == 0) {
        int lo = 0, hi = N_NODES;
        while (lo < hi) { int mid = (lo + hi) >> 1; if (batch[mid] < g) lo = mid + 1; else hi = mid; }
        range[0] = lo;
        hi = N_NODES;
        while (lo < hi) { int mid = (lo + hi) >> 1; if (batch[mid] < g + 1) lo = mid + 1; else hi = mid; }
        range[1] = lo;
    }
    __syncthreads();
    int lo = range[0], hi = range[1];
    float s0 = 0.f, s1 = 0.f, s2 = 0.f, s3 = 0.f;
    int n = lo;
    for (; n + 4 <= hi; n += 4) {
        s0 += h[(size_t)n * HID + tid];
        s1 += h[(size_t)(n + 1) * HID + tid];
        s2 += h[(size_t)(n + 2) * HID + tid];
        s3 += h[(size_t)(n + 3) * HID + tid];
    }
    for (; n < hi; ++n) s0 += h[(size_t)n * HID + tid];
    float s = (s0 + s1) + (s2 + s3);
    int cnt = hi - lo; if (cnt < 1) cnt = 1;
    hg[tid] = s / (float)cnt;
    __syncthreads();
    if (tid < 64) {
        float a = b0[tid];
        for (int i = 0; i < 128; ++i) a += hg[i] * w0[tid * 128 + i];
        z0[tid] = fmaxf(a, 0.f);
    }
    __syncthreads();
    if (tid < 32) {
        float a = b1[tid];
        for (int i = 0; i < 64; ++i) a += z0[i] * w1[tid * 64 + i];
        z1[tid] = fmaxf(a, 0.f);
    }
    __syncthreads();
    if (tid < 10) {
        float a = b2[tid];
        for (int i = 0; i < 32; ++i) a += z1[i] * w2[tid * 32 + i];
        out[g * NC + tid] = a;
    }
}

// ----------------------------------------------------------------- launch
extern "C" void kernel_launch(void* const* d_in, const int* in_sizes, int n_in,
                              void* d_out, int out_size, void* d_ws, size_t ws_size,
                              hipStream_t stream) {
    const float* feature = (const float*)d_in[0];
    const int*   edge    = (const int*)d_in[1];
    const int*   row     = edge;
    const int*   col     = edge + N_EDGES;
    const int*   batch   = (const int*)d_in[2];
    const float* emb_w   = (const float*)d_in[3];
    const float* emb_b   = (const float*)d_in[4];
    const float* fc_w    = (const float*)d_in[5];
    const float* mu      = (const float*)d_in[6];
    const float* isig    = (const float*)d_in[7];
    const float* gamma   = (const float*)d_in[8];
    const float* beta    = (const float*)d_in[9];
    const float* pp_w    = (const float*)d_in[10];
    const float* pp_b    = (const float*)d_in[11];
    const float* mw0     = (const float*)d_in[12];
    const float* mb0     = (const float*)d_in[13];
    const float* mw1     = (const float*)d_in[14];
    const float* mb1     = (const float*)d_in[15];
    const float* mw2     = (const float*)d_in[16];
    const float* mb2     = (const float*)d_in[17];
    float* out = (float*)d_out;

    // workspace carve-up (256B aligned)
    char* ws = (char*)d_ws;
    size_t off = 0;
    auto carve = [&](size_t bytes) { size_t o = off; off = (off + bytes + 255) & ~(size_t)255; return o; };
    float* h        = (float*)(ws + carve((size_t)N_NODES * HID * 4));
    _Float16* h16   = (_Float16*)(ws + carve((size_t)N_NODES * HID * 2));
    unsigned short* u_hi = (unsigned short*)(ws + carve((size_t)N_NODES * NK * HID * 2));
    unsigned short* u_lo = (unsigned short*)(ws + carve((size_t)N_NODES * NK * HID * 2));
    float* agg      = (float*)(ws + carve((size_t)N_NODES * HID * 4));
    float2* pseudo_s= (float2*)(ws + carve((size_t)N_EDGES * 2 * 4));
    float4* wE      = (float4*)(ws + carve((size_t)NL * N_EDGES * 4 * 4));
    unsigned short* w2t_hi = (unsigned short*)(ws + carve((size_t)NL * HID * NK * HID * 2));
    unsigned short* w2t_lo = (unsigned short*)(ws + carve((size_t)NL * HID * NK * HID * 2));
    unsigned short* f_hi   = (unsigned short*)(ws + carve((size_t)N_NODES * HID * 2));
    unsigned short* f_lo   = (unsigned short*)(ws + carve((size_t)N_NODES * HID * 2));
    unsigned short* e_hi   = (unsigned short*)(ws + carve((size_t)HID * HID * 2));
    unsigned short* e_lo   = (unsigned short*)(ws + carve((size_t)HID * HID * 2));
    int* degr       = (int*)(ws + carve((size_t)N_NODES * 4));
    int* degc       = (int*)(ws + carve((size_t)N_NODES * 4));
    int* csr_off    = (int*)(ws + carve((size_t)(N_NODES + 1) * 4));
    int* cursor     = (int*)(ws + carve((size_t)N_NODES * 4));
    int* row_off    = (int*)(ws + carve((size_t)N_EDGES * 4));
    int* blocksum   = (int*)(ws + carve((size_t)SCAN_G * 4));
    float* bnsum    = (float*)(ws + carve((size_t)NL * 2 * HID * 4));
    (void)ws_size; (void)in_sizes; (void)n_in; (void)out_size;

    hipMemsetAsync(degr, 0, (size_t)N_NODES * 4, stream);
    hipMemsetAsync(degc, 0, (size_t)N_NODES * 4, stream);
    hipMemsetAsync(bnsum, 0, (size_t)NL * 2 * HID * 4, stream);

    degrees_kernel<<<(N_EDGES + 255) / 256, 256, 0, stream>>>(row, col, degr, degc);
    scan1_kernel<<<SCAN_G, 256, 0, stream>>>(degc, csr_off, blocksum);
    scan2_kernel<<<1, 256, 0, stream>>>(blocksum);
    scan3_kernel<<<SCAN_G, 256, 0, stream>>>(blocksum, csr_off, cursor);
    fill_csr_kernel<<<(N_EDGES + 255) / 256, 256, 0, stream>>>(row, col, degr, degc, cursor, row_off, pseudo_s);
    edge_w_all_kernel<<<(N_EDGES + 255) / 256, 256, 0, stream>>>(pseudo_s, pp_w, pp_b, mu, isig, wE);

    split_kernel<<<(N_NODES * HID + 255) / 256, 256, 0, stream>>>(feature, f_hi, f_lo, N_NODES * HID);
    split_kernel<<<(HID * HID + 255) / 256, 256, 0, stream>>>(emb_w, e_hi, e_lo, HID * HID);
    transpose_split_fc_kernel<<<(NL * NK * HID * HID + 255) / 256, 256, 0, stream>>>(fc_w, w2t_hi, w2t_lo);

    // h = feature @ emb_w^T + emb_b (writes fp32 h and fp16 shadow)
    gemm_mfma_kernel<<<(N_NODES + 127) / 128, 256, 0, stream>>>(
        f_hi, f_lo, e_hi, e_lo, emb_b, h, h16, nullptr, N_NODES, HID);

    for (int l = 0; l < NL; ++l) {
        aggregate_kernel<<<(N_NODES + 3) / 4, 256, 0, stream>>>(
            csr_off, row_off, wE + (size_t)l * N_EDGES, (const char*)h16, u_hi, u_lo);
        gemm_mfma_kernel<<<(N_NODES + 127) / 128, 256, 0, stream>>>(
            u_hi, u_lo, w2t_hi + (size_t)l * HID * NK * HID, w2t_lo + (size_t)l * HID * NK * HID,
            nullptr, agg, nullptr, bnsum + l * 2 * HID, N_NODES, NK * HID);
        bn_apply_kernel<<<(N_NODES * HID / 4 + 255) / 256, 256, 0, stream>>>(
            (float4*)h, (half4v*)h16, (const float4*)agg, bnsum + l * 2 * HID,
            gamma + l * HID, beta + l * HID);
    }

    readout_mlp_kernel<<<N_GRAPHS, 128, 0, stream>>>(h, batch, mw0, mb0, mw1, mb1, mw2, mb2, out);
}

// Round 7
// 631.811 us; speedup vs baseline: 1.3903x; 1.0731x over previous
//
#include <hip/hip_runtime.h>
#include <hip/hip_bf16.h>

#define N_NODES 50000
#define N_EDGES 800000
#define N_GRAPHS 128
#define HID 128
#define NK 3
#define NL 4
#define NC 10
#define BN_EPS 1e-5f
#define SCAN_G ((N_NODES + 255) / 256)

// histogram bucketing
#define BKT_SZ 8192
#define NBKT 7                    // ceil(50000/8192)
#define NCHK 32
#define CHK_E (N_EDGES / NCHK)    // 25000

typedef __attribute__((ext_vector_type(8))) _Float16 half8;
typedef __attribute__((ext_vector_type(4))) float floatx4;
typedef __attribute__((ext_vector_type(2))) _Float16 half2v;
typedef __attribute__((ext_vector_type(4))) _Float16 half4v;

__device__ __forceinline__ float tanh_fast(float x) {
    float ax = fabsf(x);
    float t = __expf(-2.0f * ax);
    float r = (1.0f - t) / (1.0f + t);
    return copysignf(r, x);
}

// ---------------- bucketed histogram: per-(bucket,chunk) partials, LDS atomics only
__global__ __launch_bounds__(256) void hist_part_kernel(const int* __restrict__ row,
                                                        const int* __restrict__ col,
                                                        int* __restrict__ pr,
                                                        int* __restrict__ pc) {
    __shared__ int hr[BKT_SZ], hc[BKT_SZ];
    int b = blockIdx.x / NCHK, c = blockIdx.x % NCHK;
    int tid = threadIdx.x;
    for (int i = tid; i < BKT_SZ; i += 256) { hr[i] = 0; hc[i] = 0; }
    __syncthreads();
    int base = b * BKT_SZ;
    int e0 = c * CHK_E, e1 = e0 + CHK_E;
    for (int e = e0 + tid; e < e1; e += 256) {
        int ur = row[e] - base;
        int uc = col[e] - base;
        if ((unsigned)ur < BKT_SZ) atomicAdd(&hr[ur], 1);
        if ((unsigned)uc < BKT_SZ) atomicAdd(&hc[uc], 1);
    }
    __syncthreads();
    size_t ob = ((size_t)b * NCHK + c) * BKT_SZ;
    for (int i = tid; i < BKT_SZ; i += 256) {
        pr[ob + i] = hr[i];
        pc[ob + i] = hc[i];
    }
}

// reduce partials -> degr/degc; in-place exclusive scan of pc over chunks
__global__ __launch_bounds__(256) void hist_reduce_kernel(const int* __restrict__ pr,
                                                          int* __restrict__ pc,
                                                          int* __restrict__ degr,
                                                          int* __restrict__ degc) {
    int n = blockIdx.x * 256 + threadIdx.x;
    if (n >= N_NODES) return;
    int b = n / BKT_SZ, off = n - b * BKT_SZ;
    size_t base = (size_t)b * NCHK * BKT_SZ + off;
    int sr = 0, sc = 0;
    for (int c = 0; c < NCHK; ++c) {
        size_t idx = base + (size_t)c * BKT_SZ;
        sr += pr[idx];
        int v = pc[idx];
        pc[idx] = sc;          // exclusive chunk prefix
        sc += v;
    }
    degr[n] = sr;
    degc[n] = sc;
}

// ------------------------------------------------ hierarchical scan (3 kernels)
__global__ __launch_bounds__(256) void scan1_kernel(const int* __restrict__ degc,
                                                    int* __restrict__ csr_off,
                                                    int* __restrict__ blocksum) {
    __shared__ int buf[256];
    int tid = threadIdx.x;
    int i = blockIdx.x * 256 + tid;
    int v = (i < N_NODES) ? degc[i] : 0;
    buf[tid] = v;
    __syncthreads();
    for (int d = 1; d < 256; d <<= 1) {
        int t = (tid >= d) ? buf[tid - d] : 0;
        __syncthreads();
        buf[tid] += t;
        __syncthreads();
    }
    if (i < N_NODES) csr_off[i] = buf[tid] - v;
    if (tid == 255) blocksum[blockIdx.x] = buf[255];
}

__global__ __launch_bounds__(256) void scan2_kernel(int* __restrict__ blocksum) {
    __shared__ int buf[256];
    int tid = threadIdx.x;
    int v = (tid < SCAN_G) ? blocksum[tid] : 0;
    buf[tid] = v;
    __syncthreads();
    for (int d = 1; d < 256; d <<= 1) {
        int t = (tid >= d) ? buf[tid - d] : 0;
        __syncthreads();
        buf[tid] += t;
        __syncthreads();
    }
    if (tid < SCAN_G) blocksum[tid] = buf[tid] - v;   // exclusive, in place
}

__global__ __launch_bounds__(256) void scan3_kernel(const int* __restrict__ blocksum,
                                                    int* __restrict__ csr_off) {
    int i = blockIdx.x * 256 + threadIdx.x;
    if (i < N_NODES) csr_off[i] += blocksum[blockIdx.x];
    if (i == 0) csr_off[N_NODES] = N_EDGES;
}

// ------------- bucketed CSR fill: LDS cursors only, no global atomics
__global__ __launch_bounds__(256) void fill_bucket_kernel(const int* __restrict__ row,
                                                          const int* __restrict__ col,
                                                          const int* __restrict__ degr,
                                                          const int* __restrict__ degc,
                                                          const int* __restrict__ csr_off,
                                                          const int* __restrict__ pc,
                                                          int* __restrict__ row_off,
                                                          float2* __restrict__ pseudo_s) {
    __shared__ int cur[BKT_SZ];
    int b = blockIdx.x / NCHK, c = blockIdx.x % NCHK;
    int tid = threadIdx.x;
    int base = b * BKT_SZ;
    size_t ob = ((size_t)b * NCHK + c) * BKT_SZ;
    for (int i = tid; i < BKT_SZ; i += 256) {
        int node = base + i;
        cur[i] = (node < N_NODES) ? (csr_off[node] + pc[ob + i]) : 0;
    }
    __syncthreads();
    int e0 = c * CHK_E, e1 = e0 + CHK_E;
    for (int e = e0 + tid; e < e1; e += 256) {
        int v = col[e];
        int uv = v - base;
        if ((unsigned)uv < BKT_SZ) {
            int r = row[e];
            int pos = atomicAdd(&cur[uv], 1);
            row_off[pos] = r << 8;   // byte offset into fp16 h row (256 B)
            pseudo_s[pos] = make_float2(rsqrtf((float)degr[r] + 1.0f),
                                        rsqrtf((float)degc[v] + 1.0f));
        }
    }
}

// -------------------- per-edge weights for ALL layers in one pass
__global__ void edge_w_all_kernel(const float2* __restrict__ ps_in,
                                  const float* __restrict__ pp_w, const float* __restrict__ pp_b,
                                  const float* __restrict__ mu, const float* __restrict__ isig,
                                  float4* __restrict__ wE) {
    int e = blockIdx.x * blockDim.x + threadIdx.x;
    if (e >= N_EDGES) return;
    float2 p = ps_in[e];
#pragma unroll
    for (int l = 0; l < NL; ++l) {
        float ps0 = tanh_fast(p.x * pp_w[l * 4 + 0] + p.y * pp_w[l * 4 + 1] + pp_b[l * 2 + 0]);
        float ps1 = tanh_fast(p.x * pp_w[l * 4 + 2] + p.y * pp_w[l * 4 + 3] + pp_b[l * 2 + 1]);
        float w[NK];
#pragma unroll
        for (int k = 0; k < NK; ++k) {
            float d0 = ps0 - mu[l * 6 + k * 2 + 0], d1 = ps1 - mu[l * 6 + k * 2 + 1];
            float s0 = isig[l * 6 + k * 2 + 0],     s1 = isig[l * 6 + k * 2 + 1];
            w[k] = __expf(-0.5f * (d0 * d0 * s0 * s0 + d1 * d1 * s1 * s1));
        }
        wE[(size_t)l * N_EDGES + e] = make_float4(w[0], w[1], w[2], 0.0f);
    }
}

// ------------------------------- fp32 -> fp16 convert (vectorized)
__global__ void cvt16_kernel(const float4* __restrict__ src, half4v* __restrict__ dst, int n4) {
    int i = blockIdx.x * blockDim.x + threadIdx.x;
    if (i >= n4) return;
    float4 f = src[i];
    half4v o;
    o.x = (_Float16)f.x; o.y = (_Float16)f.y; o.z = (_Float16)f.z; o.w = (_Float16)f.w;
    dst[i] = o;
}

// ---------- fc_w transpose -> fp16: w2t[l][j][k*H+i] = fc_w[l][k*H+j][i]
__global__ void transpose_fc16_kernel(const float* __restrict__ fc_w,
                                      _Float16* __restrict__ w2t) {
    int idx = blockIdx.x * blockDim.x + threadIdx.x;
    if (idx >= NL * NK * HID * HID) return;
    int i = idx & (HID - 1);
    int j = (idx >> 7) & (HID - 1);
    int kl = idx >> 14;          // l*3 + k
    int k = kl % 3;
    int l = kl / 3;
    w2t[((size_t)(l * HID + j)) * (NK * HID) + k * HID + i] = (_Float16)fc_w[idx];
}

// -------------------------------------------------- fp16 MFMA GEMM
// C[M x 128] = A[M x Kd] @ W[128 x Kd]^T (+bias). 128x128 block tile.
// Optional fused BN stats; optional fp16 shadow of C.
__global__ __launch_bounds__(256) void gemm_f16_kernel(
        const _Float16* __restrict__ A, const _Float16* __restrict__ W,
        const float* __restrict__ bias, float* __restrict__ C, _Float16* __restrict__ C16,
        float* __restrict__ bnsum, int M, int Kd) {
    __shared__ _Float16 sA[128 * 40], sB[128 * 40];   // stride 40 halfs
    __shared__ float bsum[HID], bsq[HID];
    int tid = threadIdx.x;
    if (bnsum && tid < HID) { bsum[tid] = 0.f; bsq[tid] = 0.f; }
    int bm = blockIdx.x * 128;
    int wave = tid >> 6, lane = tid & 63;
    int ln = lane & 15, quad = lane >> 4;
    int wy = wave >> 1, wx = wave & 1;
    int srow = tid >> 2, scol = (tid & 3) << 3;
    floatx4 acc[4][4] = {};
    const half8 zv = {0, 0, 0, 0, 0, 0, 0, 0};

    half8 pA[2], pB[2];
    bool av0 = (bm + srow) < M, av1 = (bm + srow + 64) < M;
    const size_t aoff0 = (size_t)(bm + srow) * Kd + scol;
    const size_t aoff1 = (size_t)(bm + srow + 64) * Kd + scol;
    const size_t woff0 = (size_t)srow * Kd + scol;
    const size_t woff1 = (size_t)(srow + 64) * Kd + scol;

#define LOAD_TILE(K0)                                                          \
    do {                                                                       \
        pB[0] = *(const half8*)(W + woff0 + (K0));                             \
        pB[1] = *(const half8*)(W + woff1 + (K0));                             \
        pA[0] = av0 ? *(const half8*)(A + aoff0 + (K0)) : zv;                  \
        pA[1] = av1 ? *(const half8*)(A + aoff1 + (K0)) : zv;                  \
    } while (0)

    LOAD_TILE(0);
    for (int k0 = 0; k0 < Kd; k0 += 32) {
        __syncthreads();
#pragma unroll
        for (int rep = 0; rep < 2; ++rep) {
            int r = srow + rep * 64;
            *(half8*)&sA[r * 40 + scol] = pA[rep];
            *(half8*)&sB[r * 40 + scol] = pB[rep];
        }
        __syncthreads();
        if (k0 + 32 < Kd) LOAD_TILE(k0 + 32);   // overlaps with MFMA below
        half8 a[4], b[4];
        int kq = quad * 8;
#pragma unroll
        for (int i = 0; i < 4; ++i) {
            a[i] = *(const half8*)&sA[(wy * 64 + i * 16 + ln) * 40 + kq];
            b[i] = *(const half8*)&sB[(wx * 64 + i * 16 + ln) * 40 + kq];
        }
#pragma unroll
        for (int i = 0; i < 4; ++i)
#pragma unroll
            for (int j = 0; j < 4; ++j)
                acc[i][j] = __builtin_amdgcn_mfma_f32_16x16x32_f16(a[i], b[j], acc[i][j], 0, 0, 0);
    }
#undef LOAD_TILE

    // epilogue: C/D layout col = lane&15, row = quad*4 + reg
#pragma unroll
    for (int j = 0; j < 4; ++j) {
        int gc = wx * 64 + j * 16 + ln;
        float bv = bias ? bias[gc] : 0.f;
#pragma unroll
        for (int i = 0; i < 4; ++i) {
#pragma unroll
            for (int r = 0; r < 4; ++r) {
                int gr = bm + wy * 64 + i * 16 + quad * 4 + r;
                if (gr < M) {
                    float v = acc[i][j][r] + bv;
                    C[(size_t)gr * HID + gc] = v;
                    if (C16) C16[(size_t)gr * HID + gc] = (_Float16)v;
                }
            }
        }
    }
    if (bnsum) {
        // rows beyond M accumulated zeros (A loaded as 0, no bias) -> safe
#pragma unroll
        for (int j = 0; j < 4; ++j) {
            float s = 0.f, q = 0.f;
#pragma unroll
            for (int i = 0; i < 4; ++i)
#pragma unroll
                for (int r = 0; r < 4; ++r) { float v = acc[i][j][r]; s += v; q += v * v; }
            s += __shfl_xor(s, 16); s += __shfl_xor(s, 32);
            q += __shfl_xor(q, 16); q += __shfl_xor(q, 32);
            if (quad == 0) {
                atomicAdd(&bsum[wx * 64 + j * 16 + ln], s);
                atomicAdd(&bsq[wx * 64 + j * 16 + ln], q);
            }
        }
        __syncthreads();
        if (tid < HID) {
            atomicAdd(&bnsum[tid],       bsum[tid]);
            atomicAdd(&bnsum[HID + tid], bsq[tid]);
        }
    }
}

// ----------- CSR aggregation gathering fp16 h; emits u fp16 [N][384]
// metadata for up to 64 edges loaded once per wave (coalesced), broadcast via shfl
__global__ __launch_bounds__(256) void aggregate_kernel(const int* __restrict__ csr_off,
                                                        const int* __restrict__ row_off,
                                                        const float4* __restrict__ wE,
                                                        const char* __restrict__ h16,
                                                        _Float16* __restrict__ u) {
    int wave = threadIdx.x >> 6;
    int lane = threadIdx.x & 63;
    int n = blockIdx.x * 4 + wave;
    if (n >= N_NODES) return;
    int beg = csr_off[n], end = csr_off[n + 1];
    const char* hb = h16 + lane * 4;
    float2 a0 = {0.f, 0.f}, a1 = {0.f, 0.f}, a2 = {0.f, 0.f};
    for (int chunk = beg; chunk < end; chunk += 64) {
        int ce = chunk + lane;
        int roff = 0;
        float4 wv = make_float4(0.f, 0.f, 0.f, 0.f);
        if (ce < end) { roff = row_off[ce]; wv = wE[ce]; }
        int m = end - chunk; if (m > 64) m = 64;
        int t = 0;
        for (; t + 8 <= m; t += 8) {
            int ro[8]; float wx[8], wy[8], wz[8];
#pragma unroll
            for (int s = 0; s < 8; ++s) {
                ro[s] = __shfl(roff, t + s);
                wx[s] = __shfl(wv.x, t + s);
                wy[s] = __shfl(wv.y, t + s);
                wz[s] = __shfl(wv.z, t + s);
            }
            half2v hv[8];
#pragma unroll
            for (int s = 0; s < 8; ++s) hv[s] = *(const half2v*)(hb + (unsigned)ro[s]);
#pragma unroll
            for (int s = 0; s < 8; ++s) {
                float hx = (float)hv[s].x, hy = (float)hv[s].y;
                a0.x += wx[s] * hx; a0.y += wx[s] * hy;
                a1.x += wy[s] * hx; a1.y += wy[s] * hy;
                a2.x += wz[s] * hx; a2.y += wz[s] * hy;
            }
        }
        for (; t < m; ++t) {
            int ro = __shfl(roff, t);
            float wx = __shfl(wv.x, t), wy = __shfl(wv.y, t), wz = __shfl(wv.z, t);
            half2v hv = *(const half2v*)(hb + (unsigned)ro);
            float hx = (float)hv.x, hy = (float)hv.y;
            a0.x += wx * hx; a0.y += wx * hy;
            a1.x += wy * hx; a1.y += wy * hy;
            a2.x += wz * hx; a2.y += wz * hy;
        }
    }
    size_t base = (size_t)n * 384 + lane * 2;
    half2v o0, o1, o2;
    o0.x = (_Float16)a0.x; o0.y = (_Float16)a0.y;
    o1.x = (_Float16)a1.x; o1.y = (_Float16)a1.y;
    o2.x = (_Float16)a2.x; o2.y = (_Float16)a2.y;
    *(half2v*)(u + base)       = o0;
    *(half2v*)(u + base + 128) = o1;
    *(half2v*)(u + base + 256) = o2;
}

// --------------------- BN apply + ReLU + residual; also writes fp16 shadow
__global__ void bn_apply_kernel(float4* __restrict__ h4, half4v* __restrict__ h16,
                                const float4* __restrict__ agg4,
                                const float* __restrict__ bnsum,
                                const float* __restrict__ gamma, const float* __restrict__ beta) {
    int idx = blockIdx.x * blockDim.x + threadIdx.x;
    if (idx >= N_NODES * HID / 4) return;
    int c = (idx & 31) * 4;
    const float invN = 1.0f / (float)N_NODES;
    float4 a = agg4[idx];
    float4 hv = h4[idx];
    float av[4] = {a.x, a.y, a.z, a.w};
    float hh[4] = {hv.x, hv.y, hv.z, hv.w};
    float o[4];
    half4v o16;
#pragma unroll
    for (int j = 0; j < 4; ++j) {
        float mean = bnsum[c + j] * invN;
        float var = bnsum[HID + c + j] * invN - mean * mean;
        float hn = (av[j] - mean) * rsqrtf(var + BN_EPS) * gamma[c + j] + beta[c + j];
        o[j] = hh[j] + fmaxf(hn, 0.f);
        o16[j] = (_Float16)o[j];
    }
    h4[idx] = make_float4(o[0], o[1], o[2], o[3]);
    h16[idx] = o16;
}

// -------------------------------------------- fused readout + 3-layer MLP
__global__ __launch_bounds__(128) void readout_mlp_kernel(const float* __restrict__ h,
                                                          const int* __restrict__ batch,
                                                          const float* __restrict__ w0, const float* __restrict__ b0,
                                                          const float* __restrict__ w1, const float* __restrict__ b1,
                                                          const float* __restrict__ w2, const float* __restrict__ b2,
                                                          float* __restrict__ out) {
    __shared__ float hg[128];
    __shared__ float z0[64];
    __shared__ float z1[32];
    __shared__ int range[2];
    int g = blockIdx.x;
    int tid = threadIdx.x;
    if (tid == 0) {
        int lo = 0, hi = N_NODES;
        while (lo < hi) { int mid = (lo + hi) >> 1; if (batch[mid] < g) lo = mid + 1; else hi = mid; }
        range[0] = lo;
        hi = N_NODES;
        while (lo < hi) { int mid = (lo + hi) >> 1; if (batch[mid] < g + 1) lo = mid + 1; else hi = mid; }
        range[1] = lo;
    }
    __syncthreads();
    int lo = range[0], hi = range[1];
    float s0 = 0.f, s1 = 0.f, s2 = 0.f, s3 = 0.f;
    int n = lo;
    for (; n + 4 <= hi; n += 4) {
        s0 += h[(size_t)n * HID + tid];
        s1 += h[(size_t)(n + 1) * HID + tid];
        s2 += h[(size_t)(n + 2) * HID + tid];
        s3 += h[(size_t)(n + 3) * HID + tid];
    }
    for (; n < hi; ++n) s0 += h[(size_t)n * HID + tid];
    float s = (s0 + s1) + (s2 + s3);
    int cnt = hi - lo; if (cnt < 1) cnt = 1;
    hg[tid] = s / (float)cnt;
    __syncthreads();
    if (tid < 64) {
        float a = b0[tid];
        for (int i = 0; i < 128; ++i) a += hg[i] * w0[tid * 128 + i];
        z0[tid] = fmaxf(a, 0.f);
    }
    __syncthreads();
    if (tid < 32) {
        float a = b1[tid];
        for (int i = 0; i < 64; ++i) a += z0[i] * w1[tid * 64 + i];
        z1[tid] = fmaxf(a, 0.f);
    }
    __syncthreads();
    if (tid < 10) {
        float a = b2[tid];
        for (int i = 0; i < 32; ++i) a += z1[i] * w2[tid * 32 + i];
        out[g * NC + tid] = a;
    }
}

// ----------------------------------------------------------------- launch
extern "C" void kernel_launch(void* const* d_in, const int* in_sizes, int n_in,
                              void* d_out, int out_size, void* d_ws, size_t ws_size,
                              hipStream_t stream) {
    const float* feature = (const float*)d_in[0];
    const int*   edge    = (const int*)d_in[1];
    const int*   row     = edge;
    const int*   col     = edge + N_EDGES;
    const int*   batch   = (const int*)d_in[2];
    const float* emb_w   = (const float*)d_in[3];
    const float* emb_b   = (const float*)d_in[4];
    const float* fc_w    = (const float*)d_in[5];
    const float* mu      = (const float*)d_in[6];
    const float* isig    = (const float*)d_in[7];
    const float* gamma   = (const float*)d_in[8];
    const float* beta    = (const float*)d_in[9];
    const float* pp_w    = (const float*)d_in[10];
    const float* pp_b    = (const float*)d_in[11];
    const float* mw0     = (const float*)d_in[12];
    const float* mb0     = (const float*)d_in[13];
    const float* mw1     = (const float*)d_in[14];
    const float* mb1     = (const float*)d_in[15];
    const float* mw2     = (const float*)d_in[16];
    const float* mb2     = (const float*)d_in[17];
    float* out = (float*)d_out;

    // workspace carve-up (256B aligned)
    char* ws = (char*)d_ws;
    size_t off = 0;
    auto carve = [&](size_t bytes) { size_t o = off; off = (off + bytes + 255) & ~(size_t)255; return o; };
    float* h        = (float*)(ws + carve((size_t)N_NODES * HID * 4));
    _Float16* h16   = (_Float16*)(ws + carve((size_t)N_NODES * HID * 2));
    _Float16* u     = (_Float16*)(ws + carve((size_t)N_NODES * NK * HID * 2));
    float* agg      = (float*)(ws + carve((size_t)N_NODES * HID * 4));
    float2* pseudo_s= (float2*)(ws + carve((size_t)N_EDGES * 2 * 4));
    float4* wE      = (float4*)(ws + carve((size_t)NL * N_EDGES * 4 * 4));
    _Float16* w2t   = (_Float16*)(ws + carve((size_t)NL * HID * NK * HID * 2));
    _Float16* f16   = (_Float16*)(ws + carve((size_t)N_NODES * HID * 2));
    _Float16* e16   = (_Float16*)(ws + carve((size_t)HID * HID * 2));
    int* degr       = (int*)(ws + carve((size_t)N_NODES * 4));
    int* degc       = (int*)(ws + carve((size_t)N_NODES * 4));
    int* csr_off    = (int*)(ws + carve((size_t)(N_NODES + 1) * 4));
    int* row_off    = (int*)(ws + carve((size_t)N_EDGES * 4));
    int* blocksum   = (int*)(ws + carve((size_t)SCAN_G * 4));
    int* pr         = (int*)(ws + carve((size_t)NBKT * NCHK * BKT_SZ * 4));
    int* pc         = (int*)(ws + carve((size_t)NBKT * NCHK * BKT_SZ * 4));
    float* bnsum    = (float*)(ws + carve((size_t)NL * 2 * HID * 4));
    (void)ws_size; (void)in_sizes; (void)n_in; (void)out_size;

    hipMemsetAsync(bnsum, 0, (size_t)NL * 2 * HID * 4, stream);

    hist_part_kernel<<<NBKT * NCHK, 256, 0, stream>>>(row, col, pr, pc);
    hist_reduce_kernel<<<(N_NODES + 255) / 256, 256, 0, stream>>>(pr, pc, degr, degc);
    scan1_kernel<<<SCAN_G, 256, 0, stream>>>(degc, csr_off, blocksum);
    scan2_kernel<<<1, 256, 0, stream>>>(blocksum);
    scan3_kernel<<<SCAN_G, 256, 0, stream>>>(blocksum, csr_off);
    fill_bucket_kernel<<<NBKT * NCHK, 256, 0, stream>>>(row, col, degr, degc, csr_off, pc,
                                                        row_off, pseudo_s);
    edge_w_all_kernel<<<(N_EDGES + 255) / 256, 256, 0, stream>>>(pseudo_s, pp_w, pp_b, mu, isig, wE);

    cvt16_kernel<<<(N_NODES * HID / 4 + 255) / 256, 256, 0, stream>>>(
        (const float4*)feature, (half4v*)f16, N_NODES * HID / 4);
    cvt16_kernel<<<(HID * HID / 4 + 255) / 256, 256, 0, stream>>>(
        (const float4*)emb_w, (half4v*)e16, HID * HID / 4);
    transpose_fc16_kernel<<<(NL * NK * HID * HID + 255) / 256, 256, 0, stream>>>(fc_w, w2t);

    // h = feature @ emb_w^T + emb_b (writes fp32 h and fp16 shadow)
    gemm_f16_kernel<<<(N_NODES + 127) / 128, 256, 0, stream>>>(
        f16, e16, emb_b, h, h16, nullptr, N_NODES, HID);

    for (int l = 0; l < NL; ++l) {
        aggregate_kernel<<<(N_NODES + 3) / 4, 256, 0, stream>>>(
            csr_off, row_off, wE + (size_t)l * N_EDGES, (const char*)h16, u);
        gemm_f16_kernel<<<(N_NODES + 127) / 128, 256, 0, stream>>>(
            u, w2t + (size_t)l * HID * NK * HID, nullptr, agg, nullptr,
            bnsum + l * 2 * HID, N_NODES, NK * HID);
        bn_apply_kernel<<<(N_NODES * HID / 4 + 255) / 256, 256, 0, stream>>>(
            (float4*)h, (half4v*)h16, (const float4*)agg, bnsum + l * 2 * HID,
            gamma + l * HID, beta + l * HID);
    }

    readout_mlp_kernel<<<N_GRAPHS, 128, 0, stream>>>(h, batch, mw0, mb0, mw1, mb1, mw2, mb2, out);
}